// Round 10
// baseline (9801.373 us; speedup 1.0000x reference)
//
#include <hip/hip_runtime.h>

// Problem constants (B=8, N=4096, n_points=1024, n_samples=32, D_PTS=6, MLPS=[64,64,128])
#define NPTS  4096
#define NB    8
#define NC    1024
#define NSAMP 32
#define DP    6
#define C0    9      // 3 + D_PTS
#define C3    128
#define ROWS_TOT 262144   // NB*NC*NSAMP

// Workspace layout (bytes). Requires ws_size >= ~184 MB. (R8 layout restored)
#define OFF_SS   (32ull<<10)     // 3 layers x {scale[128], shift[128]}
#define OFF_H0   (1ull<<20)      // h0: 262144 x 9 f32 (9.4 MB)
#define OFF_Y0   (16ull<<20)     // y0: 262144 x 64 f32 (67 MB)
#define OFF_Y1   (96ull<<20)     // y1: 262144 x 64 f32 (67 MB)
#define OFF_PSUM (168ull<<20)    // per-block channel sums   [C][NBLK]
#define OFF_PSQ  (172ull<<20)    // per-block channel sumsq  [C][NBLK]
#define OFF_GMX  (176ull<<20)    // per-centroid channel max [8192][128]
#define OFF_GMN  (180ull<<20)    // per-centroid channel min [8192][128]

typedef unsigned long long ull;

// Exact (no-FMA) squared distance to match numpy rounding; sum order ((x+y)+z).
__device__ __forceinline__ float sqdist_noc(float x, float y, float z,
                                            float cx, float cy, float cz) {
  #pragma clang fp contract(off)
  float dx = x - cx, dy = y - cy, dz = z - cz;
  return dx * dx + dy * dy + dz * dz;
}

// DPP move with old=self (masked/invalid lanes keep their value -> fmax identity)
template <int CTRL, int RM>
__device__ __forceinline__ float dpp_mov_f(float x) {
  int xi = __float_as_int(x);
  int r = __builtin_amdgcn_update_dpp(xi, xi, CTRL, RM, 0xf, false);
  return __int_as_float(r);
}

// Canonical gfx9 wave64 f32 max reduce; result valid in lane 63.
__device__ __forceinline__ float wave64_fmax(float x) {
  x = fmaxf(x, dpp_mov_f<0x111, 0xf>(x));  // row_shr:1
  x = fmaxf(x, dpp_mov_f<0x112, 0xf>(x));  // row_shr:2
  x = fmaxf(x, dpp_mov_f<0x114, 0xf>(x));  // row_shr:4
  x = fmaxf(x, dpp_mov_f<0x118, 0xf>(x));  // row_shr:8
  x = fmaxf(x, dpp_mov_f<0x142, 0xa>(x));  // row_bcast:15 -> rows 1,3
  x = fmaxf(x, dpp_mov_f<0x143, 0xc>(x));  // row_bcast:31 -> rows 2,3
  return x;
}

// ---------------------------------------------------------------------------
// FPS R10: ONE WAVE per batch. Lane l owns points [64l, 64l+64) in VGPRs
// (px/py/pz/h = 256 VGPRs). Block-wide argmax = in-register: tree argmax over
// 64 local pts -> f32 DPP wave max -> readlane(smax) -> ballot == smax ->
// ffsll = first (lowest-index) winner lane -> readlane coords+gidx. NO
// barriers, NO LDS key exchange (single wave; lgkmcnt orders LDS).
// Retire via scalar-uniform branch (slot from readlane is divergence-free)
// + lane-predicated cndmask. Tie-break = exact argmax-first (lane order ==
// index order; tree keeps lower index).
// ---------------------------------------------------------------------------
__global__ __launch_bounds__(64, 1)
void fps_kernel(const float* __restrict__ xyz, float* __restrict__ cent) {
  const int b = blockIdx.x;
  const int t = threadIdx.x;                    // lane 0..63
  const float* X = xyz + (size_t)b * NPTS * 3;
  float* OC = cent + (size_t)b * NC * 3;

  __shared__ float4 sxyz[NPTS];                 // 64 KB (emit + spec reads)
  __shared__ int sidx[NC];                      // 4 KB

  for (int p = t; p < NPTS; p += 64)
    sxyz[p] = make_float4(X[p * 3 + 0], X[p * 3 + 1], X[p * 3 + 2], 0.f);
  // single wave: ds_read after ds_write is ordered by lgkmcnt (no barrier)

  float px[64], py[64], pz[64], h[64];
  #pragma unroll
  for (int i = 0; i < 64; i++) {
    float4 v = sxyz[t * 64 + i];
    px[i] = v.x; py[i] = v.y; pz[i] = v.z;
    h[i] = fmaf(v.x, v.x, fmaf(v.y, v.y, v.z * v.z));   // |p|^2
  }

  int gidx_s = 0;                               // selection 0 = point 0 (seed)
  float4 c0 = sxyz[0];
  float cx = c0.x, cy = c0.y, cz = c0.z;
  if (t == 0) sidx[0] = 0;

  for (int k = 1; k < NC; k++) {
    // ---- retire gidx_s (uniform scalar -> s_cmp/s_cbranch ladder) ----
    {
      const int owner = gidx_s >> 6, slot = gidx_s & 63;
      const bool me = (t == owner);
      #pragma unroll
      for (int ch = 0; ch < 4; ch++) {
        if ((slot >> 4) == ch) {                // scalar branch
          #pragma unroll
          for (int i = 0; i < 16; i++) {
            if ((slot & 15) == i)               // scalar branch
              h[ch * 16 + i] = me ? -__builtin_inff() : h[ch * 16 + i];
          }
        }
      }
    }
    // ---- keys + tree argmax over 64 local points ----
    const float c2x = cx + cx, c2y = cy + cy, c2z = cz + cz;
    float key[64];
    #pragma unroll
    for (int i = 0; i < 64; i++)
      key[i] = fmaf(pz[i], -c2z, fmaf(py[i], -c2y, fmaf(px[i], -c2x, h[i])));
    float mk[4]; int mi[4];
    #pragma unroll
    for (int ch = 0; ch < 4; ch++) {            // per-chunk tree (16)
      float kk[16]; int ii[16];
      #pragma unroll
      for (int i = 0; i < 16; i++) { kk[i] = key[ch * 16 + i]; ii[i] = ch * 16 + i; }
      #pragma unroll
      for (int s = 1; s < 16; s <<= 1) {
        #pragma unroll
        for (int i = 0; i < 16; i += 2 * s) {
          bool tk = kk[i + s] > kk[i];          // strict > keeps first index
          kk[i] = tk ? kk[i + s] : kk[i];
          ii[i] = tk ? ii[i + s] : ii[i];
        }
      }
      mk[ch] = kk[0]; mi[ch] = ii[0];
    }
    bool t1 = mk[1] > mk[0]; float ka = t1 ? mk[1] : mk[0]; int ia = t1 ? mi[1] : mi[0];
    bool t3 = mk[3] > mk[2]; float kb = t3 ? mk[3] : mk[2]; int ib = t3 ? mi[3] : mi[2];
    bool tb = kb > ka; const float mx = tb ? kb : ka; const int mj = tb ? ib : ia;

    float4 cand = sxyz[t * 64 + mj];            // speculative; hides under reduce

    float wm = wave64_fmax(mx);
    int smax_b = __builtin_amdgcn_readlane(__float_as_int(wm), 63);
    ull bal = __ballot(__float_as_int(mx) == smax_b);
    int fl = __ffsll(bal) - 1;                  // first lane = lowest index
    gidx_s = __builtin_amdgcn_readlane(t * 64 + mj, fl);
    cx = __int_as_float(__builtin_amdgcn_readlane(__float_as_int(cand.x), fl));
    cy = __int_as_float(__builtin_amdgcn_readlane(__float_as_int(cand.y), fl));
    cz = __int_as_float(__builtin_amdgcn_readlane(__float_as_int(cand.z), fl));
    if (t == 0) sidx[k] = gidx_s;
  }
  // one-shot centroid emit (same wave -> no barrier)
  for (int i = t; i < NC; i += 64) {
    float4 cc = sxyz[sidx[i]];
    OC[i * 3 + 0] = cc.x;
    OC[i * 3 + 1] = cc.y;
    OC[i * 3 + 2] = cc.z;
  }
}

// ---------------------------------------------------------------------------
// query_ball + gather + concat (unchanged): exact stable-argsort semantics
// via the min(dist, r^2=0.04) quirk.
// ---------------------------------------------------------------------------
#define BCAP 256
__global__ __launch_bounds__(256)
void ball_kernel(const float* __restrict__ xyz, const float* __restrict__ pts,
                 const float* __restrict__ cent, float* __restrict__ h0) {
  const int blk = blockIdx.x;       // b*NC + c
  const int b = blk >> 10;
  const int t = threadIdx.x;
  const float* X = xyz + (size_t)b * NPTS * 3;
  const float* P = pts + (size_t)b * NPTS * DP;
  const float cx = cent[(size_t)blk * 3 + 0];
  const float cy = cent[(size_t)blk * 3 + 1];
  const float cz = cent[(size_t)blk * 3 + 2];

  __shared__ int scount;
  __shared__ ull skeys[BCAP];
  __shared__ ull ssorted[BCAP];
  __shared__ int sel[NSAMP];
  if (t == 0) scount = 0;
  __syncthreads();

  #pragma unroll
  for (int i = 0; i < 16; i++) {
    int j = t * 16 + i;
    float sq = sqdist_noc(X[j * 3 + 0], X[j * 3 + 1], X[j * 3 + 2], cx, cy, cz);
    if (sq < 0.0017f) {                       // conservative guard
      float d = (sq > 0.f) ? sqrtf(sq) : 0.f; // exact per-reference norm
      if (d < 0.04f) {                        // strictly inside the clip value
        int pos = atomicAdd(&scount, 1);
        if (pos < BCAP)
          skeys[pos] = ((ull)(unsigned)__float_as_int(d) << 12) | (unsigned)j;
      }
    }
  }
  __syncthreads();
  const int M = min(scount, BCAP);

  if (t < M) {                                // rank-sort inner set
    ull my = skeys[t];
    int r = 0;
    for (int j2 = 0; j2 < M; j2++) r += (skeys[j2] < my);
    ssorted[r] = my;
  }
  __syncthreads();

  if (t < NSAMP) {
    int v;
    if (t < M) {
      v = (int)(ssorted[t] & 0xFFFull);
    } else {
      int s = t - M;                          // s-th smallest non-inner index
      int idx = s;
      for (int it = 0; it < 40; it++) {
        int c = 0;
        for (int j2 = 0; j2 < M; j2++) c += ((int)(skeys[j2] & 0xFFFull) <= idx);
        int nidx = s + c;
        if (nidx == idx) break;
        idx = nidx;
      }
      v = idx;
    }
    sel[t] = v;
  }
  __syncthreads();

  float* H = h0 + (size_t)blk * NSAMP * C0;
  for (int e = t; e < NSAMP * C0; e += 256) {
    int k = e / C0;
    int c = e - k * C0;
    int j = sel[k];
    H[e] = (c < 3) ? X[j * 3 + c] : P[j * DP + (c - 3)];
  }
}

// ---------------------------------------------------------------------------
// dense0 (R8): h0 @ W[9,64] + b -> y0, fused BN partials. 64 rows/block.
// ---------------------------------------------------------------------------
__global__ __launch_bounds__(256)
void dense0_kernel(const float* __restrict__ h0, const float* __restrict__ W,
                   const float* __restrict__ bias, float* __restrict__ yout,
                   float* __restrict__ psum, float* __restrict__ psq) {
  __shared__ float xs[64 * C0];
  __shared__ float ws[C0 * 64];
  __shared__ float red[2][16][64];
  const int blk = blockIdx.x, t = threadIdx.x;
  const size_t rbase = (size_t)blk * 64;
  for (int e = t; e < 64 * C0; e += 256) xs[e] = h0[rbase * C0 + e];
  for (int e = t; e < C0 * 64; e += 256) ws[e] = W[e];
  __syncthreads();
  const int rg = t >> 4, cg = t & 15;
  float acc[4][4];
  float4 bv = *(const float4*)(bias + cg * 4);
  #pragma unroll
  for (int r = 0; r < 4; r++) { acc[r][0] = bv.x; acc[r][1] = bv.y; acc[r][2] = bv.z; acc[r][3] = bv.w; }
  #pragma unroll
  for (int k = 0; k < C0; k++) {
    float4 wv = *(const float4*)(ws + k * 64 + cg * 4);
    #pragma unroll
    for (int r = 0; r < 4; r++) {
      float x = xs[(rg * 4 + r) * C0 + k];
      acc[r][0] = fmaf(x, wv.x, acc[r][0]);
      acc[r][1] = fmaf(x, wv.y, acc[r][1]);
      acc[r][2] = fmaf(x, wv.z, acc[r][2]);
      acc[r][3] = fmaf(x, wv.w, acc[r][3]);
    }
  }
  #pragma unroll
  for (int r = 0; r < 4; r++)
    *(float4*)(yout + (rbase + rg * 4 + r) * 64 + cg * 4) =
        make_float4(acc[r][0], acc[r][1], acc[r][2], acc[r][3]);
  #pragma unroll
  for (int c4 = 0; c4 < 4; c4++) {
    float s = 0.f, q = 0.f;
    #pragma unroll
    for (int r = 0; r < 4; r++) { float v = acc[r][c4]; s += v; q = fmaf(v, v, q); }
    red[0][rg][cg * 4 + c4] = s;
    red[1][rg][cg * 4 + c4] = q;
  }
  __syncthreads();
  if (t < 64) {
    float S = 0.f, Q = 0.f;
    #pragma unroll
    for (int g = 0; g < 16; g++) { S += red[0][g][t]; Q += red[1][g][t]; }
    psum[(size_t)t * 4096 + blk] = S;
    psq [(size_t)t * 4096 + blk] = Q;
  }
}

// ---------------------------------------------------------------------------
// dense mid (R8): BN fused on load, fused BN partials; MM = per-centroid
// max/min of raw y instead of materializing (layer 2).
// ---------------------------------------------------------------------------
template <int RPB, int COUT, int CGN, int NBLKS, bool MM>
__global__ __launch_bounds__(256)
void dense_mid_kernel(const float* __restrict__ yin, const float* __restrict__ ssin,
                      const float* __restrict__ W, const float* __restrict__ bias,
                      float* __restrict__ yout,
                      float* __restrict__ psum, float* __restrict__ psq,
                      float* __restrict__ gmax, float* __restrict__ gmin) {
  constexpr int NG = 256 / CGN;
  __shared__ float xs[RPB * 68];
  __shared__ float ws[64 * COUT];
  __shared__ float scs[64], shs[64];
  __shared__ float red[2][NG][COUT];
  __shared__ float redm[MM ? 2 : 1][MM ? NG : 1][MM ? COUT : 1];
  const int blk = blockIdx.x, t = threadIdx.x;
  if (t < 64) { scs[t] = ssin[t]; shs[t] = ssin[128 + t]; }
  __syncthreads();
  const size_t rbase = (size_t)blk * RPB;
  for (int e = t; e < RPB * 64; e += 256) {
    int c = e & 63;
    float v = yin[rbase * 64 + e];
    xs[(e >> 6) * 68 + c] = fmaxf(fmaf(v, scs[c], shs[c]), 0.f);
  }
  for (int e = t; e < 64 * COUT; e += 256) ws[e] = W[e];
  __syncthreads();
  const int rg = t / CGN, cg = t % CGN;
  float acc[4][4];
  float4 bv = *(const float4*)(bias + cg * 4);
  #pragma unroll
  for (int r = 0; r < 4; r++) { acc[r][0] = bv.x; acc[r][1] = bv.y; acc[r][2] = bv.z; acc[r][3] = bv.w; }
  for (int k0 = 0; k0 < 64; k0 += 4) {
    float4 xv[4];
    #pragma unroll
    for (int r = 0; r < 4; r++)
      xv[r] = *(const float4*)(xs + (rg * 4 + r) * 68 + k0);
    #pragma unroll
    for (int kk = 0; kk < 4; kk++) {
      float4 wv = *(const float4*)(ws + (k0 + kk) * COUT + cg * 4);
      #pragma unroll
      for (int r = 0; r < 4; r++) {
        float x = (&xv[r].x)[kk];
        acc[r][0] = fmaf(x, wv.x, acc[r][0]);
        acc[r][1] = fmaf(x, wv.y, acc[r][1]);
        acc[r][2] = fmaf(x, wv.z, acc[r][2]);
        acc[r][3] = fmaf(x, wv.w, acc[r][3]);
      }
    }
  }
  if constexpr (!MM) {
    #pragma unroll
    for (int r = 0; r < 4; r++)
      *(float4*)(yout + (rbase + rg * 4 + r) * COUT + cg * 4) =
          make_float4(acc[r][0], acc[r][1], acc[r][2], acc[r][3]);
  }
  #pragma unroll
  for (int c4 = 0; c4 < 4; c4++) {
    float s = 0.f, q = 0.f;
    #pragma unroll
    for (int r = 0; r < 4; r++) { float v = acc[r][c4]; s += v; q = fmaf(v, v, q); }
    red[0][rg][cg * 4 + c4] = s;
    red[1][rg][cg * 4 + c4] = q;
    if constexpr (MM) {
      float mx = acc[0][c4], mn = acc[0][c4];
      #pragma unroll
      for (int r = 1; r < 4; r++) { mx = fmaxf(mx, acc[r][c4]); mn = fminf(mn, acc[r][c4]); }
      redm[0][rg][cg * 4 + c4] = mx;
      redm[1][rg][cg * 4 + c4] = mn;
    }
  }
  __syncthreads();
  if (t < COUT) {
    float S = 0.f, Q = 0.f;
    #pragma unroll
    for (int g = 0; g < NG; g++) { S += red[0][g][t]; Q += red[1][g][t]; }
    psum[(size_t)t * NBLKS + blk] = S;
    psq [(size_t)t * NBLKS + blk] = Q;
    if constexpr (MM) {
      float mx = redm[0][0][t], mn = redm[1][0][t];
      #pragma unroll
      for (int g = 1; g < NG; g++) { mx = fmaxf(mx, redm[0][g][t]); mn = fminf(mn, redm[1][g][t]); }
      gmax[(size_t)blk * COUT + t] = mx;
      gmin[(size_t)blk * COUT + t] = mn;
    }
  }
}

// ---------------------------------------------------------------------------
// stats finalize (unchanged)
// ---------------------------------------------------------------------------
template <int NBLK>
__global__ __launch_bounds__(256)
void stats_final_kernel(const float* __restrict__ psum, const float* __restrict__ psq,
                        const float* __restrict__ g, const float* __restrict__ be,
                        float* __restrict__ ss_out) {
  const int c = blockIdx.x, t = threadIdx.x;
  float S = 0.f, Q = 0.f;
  for (int i = t; i < NBLK; i += 256) {
    S += psum[(size_t)c * NBLK + i];
    Q += psq [(size_t)c * NBLK + i];
  }
  __shared__ float sS[256], sQ[256];
  sS[t] = S; sQ[t] = Q;
  __syncthreads();
  #pragma unroll
  for (int off = 128; off; off >>= 1) {
    if (t < off) { sS[t] += sS[t + off]; sQ[t] += sQ[t + off]; }
    __syncthreads();
  }
  if (t == 0) {
    const float inv = 1.0f / 262144.0f;
    float mean = sS[0] * inv;
    float var = sQ[0] * inv - mean * mean;
    float scale = g[c] / sqrtf(var + 1e-3f);
    ss_out[c] = scale;
    ss_out[128 + c] = be[c] - mean * scale;
  }
}

// pool finalize (unchanged)
__global__ __launch_bounds__(128)
void pool_final_kernel(const float* __restrict__ gmax, const float* __restrict__ gmin,
                       const float* __restrict__ ss2, float* __restrict__ out1) {
  const int blk = blockIdx.x, c = threadIdx.x;
  const float sc = ss2[c], sh = ss2[128 + c];
  float v = (sc >= 0.f) ? gmax[(size_t)blk * C3 + c] : gmin[(size_t)blk * C3 + c];
  out1[(size_t)blk * C3 + c] = fmaxf(fmaf(v, sc, sh), 0.f);
}

extern "C" void kernel_launch(void* const* d_in, const int* in_sizes, int n_in,
                              void* d_out, int out_size, void* d_ws, size_t ws_size,
                              hipStream_t stream) {
  const float* xyz = (const float*)d_in[0];
  const float* pts = (const float*)d_in[1];
  const float* w0 = (const float*)d_in[2];
  const float* b0 = (const float*)d_in[3];
  const float* g0 = (const float*)d_in[4];
  const float* be0 = (const float*)d_in[5];
  const float* w1 = (const float*)d_in[6];
  const float* b1 = (const float*)d_in[7];
  const float* g1 = (const float*)d_in[8];
  const float* be1 = (const float*)d_in[9];
  const float* w2 = (const float*)d_in[10];
  const float* b2 = (const float*)d_in[11];
  const float* g2 = (const float*)d_in[12];
  const float* be2 = (const float*)d_in[13];

  float* out = (float*)d_out;
  float* cent = out;                       // [8,1024,3]
  float* out1 = out + (size_t)NB * NC * 3; // [8,1024,128]

  char* ws = (char*)d_ws;
  float* ssA  = (float*)(ws + OFF_SS);
  float* h0   = (float*)(ws + OFF_H0);
  float* y0   = (float*)(ws + OFF_Y0);
  float* y1   = (float*)(ws + OFF_Y1);
  float* psum = (float*)(ws + OFF_PSUM);
  float* psq  = (float*)(ws + OFF_PSQ);
  float* gmx  = (float*)(ws + OFF_GMX);
  float* gmn  = (float*)(ws + OFF_GMN);

  fps_kernel<<<dim3(NB), dim3(64), 0, stream>>>(xyz, cent);
  ball_kernel<<<dim3(NB * NC), dim3(256), 0, stream>>>(xyz, pts, cent, h0);

  dense0_kernel<<<dim3(ROWS_TOT / 64), dim3(256), 0, stream>>>(h0, w0, b0, y0, psum, psq);
  stats_final_kernel<4096><<<dim3(64), dim3(256), 0, stream>>>(psum, psq, g0, be0, ssA + 0 * 256);

  dense_mid_kernel<64, 64, 16, 4096, false><<<dim3(ROWS_TOT / 64), dim3(256), 0, stream>>>(
      y0, ssA + 0 * 256, w1, b1, y1, psum, psq, nullptr, nullptr);
  stats_final_kernel<4096><<<dim3(64), dim3(256), 0, stream>>>(psum, psq, g1, be1, ssA + 1 * 256);

  dense_mid_kernel<32, 128, 32, 8192, true><<<dim3(ROWS_TOT / 32), dim3(256), 0, stream>>>(
      y1, ssA + 1 * 256, w2, b2, nullptr, psum, psq, gmx, gmn);
  stats_final_kernel<8192><<<dim3(128), dim3(256), 0, stream>>>(psum, psq, g2, be2, ssA + 2 * 256);

  pool_final_kernel<<<dim3(NB * NC), dim3(128), 0, stream>>>(gmx, gmn, ssA + 2 * 256, out1);

  (void)in_sizes; (void)n_in; (void)out_size; (void)ws_size;
}

// Round 11
// 880.802 us; speedup vs baseline: 11.1278x; 11.1278x over previous
//
#include <hip/hip_runtime.h>

// Problem constants (B=8, N=4096, n_points=1024, n_samples=32, D_PTS=6, MLPS=[64,64,128])
#define NPTS  4096
#define NB    8
#define NC    1024
#define NSAMP 32
#define DP    6
#define C0    9      // 3 + D_PTS
#define C3    128
#define ROWS_TOT 262144   // NB*NC*NSAMP

// Workspace layout (bytes). Requires ws_size >= ~184 MB.
#define OFF_SS   (32ull<<10)     // 3 layers x {scale[128], shift[128]}
#define OFF_Y0   (16ull<<20)     // y0: 262144 x 64 f32 (67 MB)
#define OFF_Y1   (96ull<<20)     // y1: 262144 x 64 f32 (67 MB)
#define OFF_PSUM (168ull<<20)    // per-block channel sums   [C][NBLK]
#define OFF_PSQ  (172ull<<20)    // per-block channel sumsq  [C][NBLK]
#define OFF_GMX  (176ull<<20)    // per-centroid channel max [8192][128]
#define OFF_GMN  (180ull<<20)    // per-centroid channel min [8192][128]

typedef unsigned long long ull;

// Exact (no-FMA) squared distance to match numpy rounding; sum order ((x+y)+z).
__device__ __forceinline__ float sqdist_noc(float x, float y, float z,
                                            float cx, float cy, float cz) {
  #pragma clang fp contract(off)
  float dx = x - cx, dy = y - cy, dz = z - cz;
  return dx * dx + dy * dy + dz * dz;
}

// DPP move with old=self (masked/invalid lanes keep their value -> fmax identity)
template <int CTRL, int RM>
__device__ __forceinline__ float dpp_mov_f(float x) {
  int xi = __float_as_int(x);
  int r = __builtin_amdgcn_update_dpp(xi, xi, CTRL, RM, 0xf, false);
  return __int_as_float(r);
}

// Canonical gfx9 wave64 f32 max reduce; result valid in lane 63.
__device__ __forceinline__ float wave64_fmax(float x) {
  x = fmaxf(x, dpp_mov_f<0x111, 0xf>(x));  // row_shr:1
  x = fmaxf(x, dpp_mov_f<0x112, 0xf>(x));  // row_shr:2
  x = fmaxf(x, dpp_mov_f<0x114, 0xf>(x));  // row_shr:4
  x = fmaxf(x, dpp_mov_f<0x118, 0xf>(x));  // row_shr:8
  x = fmaxf(x, dpp_mov_f<0x142, 0xa>(x));  // row_bcast:15 -> rows 1,3
  x = fmaxf(x, dpp_mov_f<0x143, 0xc>(x));  // row_bcast:31 -> rows 2,3
  return x;
}

// ---------------------------------------------------------------------------
// FPS (exact R8 kernel, measured 600 us): 256 thr / 4 waves, 16 pts/thread.
// Winners publish (x,y,z,key)+gidx; fold selects via cndmask (no dependent
// sxyz[last] read on the chain); tree argmax; f32 DPP reduce; speculative
// candidate-coord read hidden under the reduce; 1 barrier/step.
// ---------------------------------------------------------------------------
__global__ __launch_bounds__(256)
void fps_kernel(const float* __restrict__ xyz, float* __restrict__ cent) {
  const int b = blockIdx.x;
  const int t = threadIdx.x;
  const float* X = xyz + (size_t)b * NPTS * 3;
  float* OC = cent + (size_t)b * NC * 3;

  __shared__ float4 sxyz[NPTS];                 // 64 KB
  __shared__ float4 wkc[2][4];                  // per-wave (x,y,z,key), parity-dbuf
  __shared__ alignas(16) int wki[2][4];         // per-wave winner gidx
  __shared__ int sidx[NC];                      // 4 KB

  for (int p = t; p < NPTS; p += 256)
    sxyz[p] = make_float4(X[p * 3 + 0], X[p * 3 + 1], X[p * 3 + 2], 0.f);
  __syncthreads();

  float px[16], py[16], pz[16], h[16];
  #pragma unroll
  for (int i = 0; i < 16; i++) {
    float4 v = sxyz[t * 16 + i];
    px[i] = v.x; py[i] = v.y; pz[i] = v.z;
    h[i] = fmaf(v.x, v.x, fmaf(v.y, v.y, v.z * v.z));   // |p|^2
  }

  const int wv = t >> 6;
  float4 c;   // current centroid (x,y,z,*)

  auto step_body = [&](int pw_) {
    const float c2x = c.x + c.x, c2y = c.y + c.y, c2z = c.z + c.z;
    float key[16]; int idx[16];
    #pragma unroll
    for (int i = 0; i < 16; i++) {
      key[i] = fmaf(pz[i], -c2z, fmaf(py[i], -c2y, fmaf(px[i], -c2x, h[i])));
      idx[i] = i;
    }
    #pragma unroll
    for (int s = 1; s < 16; s <<= 1) {          // tree argmax, first-max ties
      #pragma unroll
      for (int i = 0; i < 16; i += 2 * s) {
        bool tk = key[i + s] > key[i];
        key[i] = tk ? key[i + s] : key[i];
        idx[i] = tk ? idx[i + s] : idx[i];
      }
    }
    const float mx = key[0];
    const int mj = idx[0];
    float4 cand = sxyz[(t << 4) + mj];          // speculative; hides under reduce
    float wm = wave64_fmax(mx);
    float smax = __int_as_float(__builtin_amdgcn_readlane(__float_as_int(wm), 63));
    if (mx == smax) {                           // winner lane(s) of this wave
      wkc[pw_][wv] = make_float4(cand.x, cand.y, cand.z, smax);
      wki[pw_][wv] = (t << 4) + mj;
    }
  };

  auto fold = [&](int pr_) -> int {
    float4 q0 = wkc[pr_][0], q1 = wkc[pr_][1];
    float4 q2 = wkc[pr_][2], q3 = wkc[pr_][3];
    const int4 ii = *(const int4*)&wki[pr_][0];
    bool g1 = q1.w > q0.w; float4 ca = g1 ? q1 : q0; int ia = g1 ? ii.y : ii.x;
    bool g3 = q3.w > q2.w; float4 cb = g3 ? q3 : q2; int ib = g3 ? ii.w : ii.z;
    bool gb = cb.w > ca.w; c = gb ? cb : ca; return gb ? ib : ia;
  };

  // ---- iteration 1: selection 0 is point 0 (seed) ----
  if (t == 0) { sidx[0] = 0; h[0] = -__builtin_inff(); }   // retire point 0
  c = sxyz[0];
  step_body(1);                                 // publish par = 1&1
  __syncthreads();

  for (int k = 2; k < NC; k++) {
    const int pr = (k - 1) & 1, pw = k & 1;
    int gidx = fold(pr);                        // selection k-1
    if (t == 0) sidx[k - 1] = gidx;
    if ((gidx >> 4) == t) {                     // retire: -INF loses everything
      int m = gidx & 15;
      #pragma unroll
      for (int i = 0; i < 16; i++)
        if (i == m) h[i] = -__builtin_inff();
    }
    step_body(pw);
    __syncthreads();
  }
  {                                             // epilogue: selection 1023
    int gidx = fold(1023 & 1);
    if (t == 0) sidx[NC - 1] = gidx;
  }
  __syncthreads();
  for (int i = t; i < NC; i += 256) {           // one-shot centroid emit
    float4 cc = sxyz[sidx[i]];
    OC[i * 3 + 0] = cc.x;
    OC[i * 3 + 1] = cc.y;
    OC[i * 3 + 2] = cc.z;
  }
}

// ---------------------------------------------------------------------------
// ball + dense0 FUSED: one block per centroid. query_ball (exact stable-
// argsort semantics via the min(dist,0.04) quirk) -> gather h-rows to LDS ->
// y0 = h @ W0 + b0 (k-ascending fmaf, identical chain to the old dense0) ->
// y0 written for dense_mid1 + BN0 partials. h0 never materialized.
// ---------------------------------------------------------------------------
#define BCAP 256
__global__ __launch_bounds__(256)
void ball_dense0_kernel(const float* __restrict__ xyz, const float* __restrict__ pts,
                        const float* __restrict__ cent,
                        const float* __restrict__ W0, const float* __restrict__ b0,
                        float* __restrict__ y0,
                        float* __restrict__ psum, float* __restrict__ psq) {
  const int blk = blockIdx.x;       // b*NC + c
  const int b = blk >> 10;
  const int t = threadIdx.x;
  const float* X = xyz + (size_t)b * NPTS * 3;
  const float* P = pts + (size_t)b * NPTS * DP;
  const float cx = cent[(size_t)blk * 3 + 0];
  const float cy = cent[(size_t)blk * 3 + 1];
  const float cz = cent[(size_t)blk * 3 + 2];

  __shared__ int scount;
  __shared__ ull skeys[BCAP];
  __shared__ ull ssorted[BCAP];
  __shared__ int sel[NSAMP];
  __shared__ float xs0[NSAMP * C0];
  __shared__ float w0s[C0 * 64];
  __shared__ float b0s[64];
  __shared__ float red[2][NSAMP][64];   // 16 KB: per-row channel values
  if (t == 0) scount = 0;
  // stage weights early (independent of ball phase)
  for (int e = t; e < C0 * 64; e += 256) w0s[e] = W0[e];
  if (t < 64) b0s[t] = b0[t];
  __syncthreads();

  #pragma unroll
  for (int i = 0; i < 16; i++) {
    int j = t * 16 + i;
    float sq = sqdist_noc(X[j * 3 + 0], X[j * 3 + 1], X[j * 3 + 2], cx, cy, cz);
    if (sq < 0.0017f) {                       // conservative guard
      float d = (sq > 0.f) ? sqrtf(sq) : 0.f; // exact per-reference norm
      if (d < 0.04f) {                        // strictly inside the clip value
        int pos = atomicAdd(&scount, 1);
        if (pos < BCAP)
          skeys[pos] = ((ull)(unsigned)__float_as_int(d) << 12) | (unsigned)j;
      }
    }
  }
  __syncthreads();
  const int M = min(scount, BCAP);

  if (t < M) {                                // rank-sort inner set
    ull my = skeys[t];
    int r = 0;
    for (int j2 = 0; j2 < M; j2++) r += (skeys[j2] < my);
    ssorted[r] = my;
  }
  __syncthreads();

  if (t < NSAMP) {
    int v;
    if (t < M) {
      v = (int)(ssorted[t] & 0xFFFull);
    } else {
      int s = t - M;                          // s-th smallest non-inner index
      int idx = s;
      for (int it = 0; it < 40; it++) {
        int c = 0;
        for (int j2 = 0; j2 < M; j2++) c += ((int)(skeys[j2] & 0xFFFull) <= idx);
        int nidx = s + c;
        if (nidx == idx) break;
        idx = nidx;
      }
      v = idx;
    }
    sel[t] = v;
  }
  __syncthreads();

  // gather h rows (xyz | pts concat) into LDS
  for (int e = t; e < NSAMP * C0; e += 256) {
    int k = e / C0;
    int cc = e - k * C0;
    int j = sel[k];
    xs0[e] = (cc < 3) ? X[j * 3 + cc] : P[j * DP + (cc - 3)];
  }
  __syncthreads();

  // dense0: row = t>>3 (32 rows), 8 channels per thread; k-ascending fmaf
  const int row = t >> 3, c8 = (t & 7) * 8;
  float a[8];
  #pragma unroll
  for (int j = 0; j < 8; j++) a[j] = b0s[c8 + j];
  #pragma unroll
  for (int k = 0; k < C0; k++) {
    float xv = xs0[row * C0 + k];
    #pragma unroll
    for (int j = 0; j < 8; j++) a[j] = fmaf(xv, w0s[k * 64 + c8 + j], a[j]);
  }
  // y0 write (coalesced float4 x2 per thread)
  float* Y = y0 + ((size_t)blk * NSAMP + row) * 64 + c8;
  *(float4*)(Y + 0) = make_float4(a[0], a[1], a[2], a[3]);
  *(float4*)(Y + 4) = make_float4(a[4], a[5], a[6], a[7]);
  // BN0 partials
  #pragma unroll
  for (int j = 0; j < 8; j++) red[0][row][c8 + j] = a[j];
  #pragma unroll
  for (int j = 0; j < 8; j++) red[1][row][c8 + j] = a[j] * a[j];
  __syncthreads();
  if (t < 64) {
    float S = 0.f, Q = 0.f;
    #pragma unroll
    for (int g = 0; g < NSAMP; g++) { S += red[0][g][t]; Q += red[1][g][t]; }
    psum[(size_t)t * 8192 + blk] = S;
    psq [(size_t)t * 8192 + blk] = Q;
  }
}

// ---------------------------------------------------------------------------
// dense mid (exact R8): BN fused on load, fused BN partials; MM = per-centroid
// max/min of raw y instead of materializing (layer 2).
// ---------------------------------------------------------------------------
template <int RPB, int COUT, int CGN, int NBLKS, bool MM>
__global__ __launch_bounds__(256)
void dense_mid_kernel(const float* __restrict__ yin, const float* __restrict__ ssin,
                      const float* __restrict__ W, const float* __restrict__ bias,
                      float* __restrict__ yout,
                      float* __restrict__ psum, float* __restrict__ psq,
                      float* __restrict__ gmax, float* __restrict__ gmin) {
  constexpr int NG = 256 / CGN;
  __shared__ float xs[RPB * 68];
  __shared__ float ws[64 * COUT];
  __shared__ float scs[64], shs[64];
  __shared__ float red[2][NG][COUT];
  __shared__ float redm[MM ? 2 : 1][MM ? NG : 1][MM ? COUT : 1];
  const int blk = blockIdx.x, t = threadIdx.x;
  if (t < 64) { scs[t] = ssin[t]; shs[t] = ssin[128 + t]; }
  __syncthreads();
  const size_t rbase = (size_t)blk * RPB;
  for (int e = t; e < RPB * 64; e += 256) {
    int c = e & 63;
    float v = yin[rbase * 64 + e];
    xs[(e >> 6) * 68 + c] = fmaxf(fmaf(v, scs[c], shs[c]), 0.f);
  }
  for (int e = t; e < 64 * COUT; e += 256) ws[e] = W[e];
  __syncthreads();
  const int rg = t / CGN, cg = t % CGN;
  float acc[4][4];
  float4 bv = *(const float4*)(bias + cg * 4);
  #pragma unroll
  for (int r = 0; r < 4; r++) { acc[r][0] = bv.x; acc[r][1] = bv.y; acc[r][2] = bv.z; acc[r][3] = bv.w; }
  for (int k0 = 0; k0 < 64; k0 += 4) {
    float4 xv[4];
    #pragma unroll
    for (int r = 0; r < 4; r++)
      xv[r] = *(const float4*)(xs + (rg * 4 + r) * 68 + k0);
    #pragma unroll
    for (int kk = 0; kk < 4; kk++) {
      float4 wv = *(const float4*)(ws + (k0 + kk) * COUT + cg * 4);
      #pragma unroll
      for (int r = 0; r < 4; r++) {
        float x = (&xv[r].x)[kk];
        acc[r][0] = fmaf(x, wv.x, acc[r][0]);
        acc[r][1] = fmaf(x, wv.y, acc[r][1]);
        acc[r][2] = fmaf(x, wv.z, acc[r][2]);
        acc[r][3] = fmaf(x, wv.w, acc[r][3]);
      }
    }
  }
  if constexpr (!MM) {
    #pragma unroll
    for (int r = 0; r < 4; r++)
      *(float4*)(yout + (rbase + rg * 4 + r) * COUT + cg * 4) =
          make_float4(acc[r][0], acc[r][1], acc[r][2], acc[r][3]);
  }
  #pragma unroll
  for (int c4 = 0; c4 < 4; c4++) {
    float s = 0.f, q = 0.f;
    #pragma unroll
    for (int r = 0; r < 4; r++) { float v = acc[r][c4]; s += v; q = fmaf(v, v, q); }
    red[0][rg][cg * 4 + c4] = s;
    red[1][rg][cg * 4 + c4] = q;
    if constexpr (MM) {
      float mx = acc[0][c4], mn = acc[0][c4];
      #pragma unroll
      for (int r = 1; r < 4; r++) { mx = fmaxf(mx, acc[r][c4]); mn = fminf(mn, acc[r][c4]); }
      redm[0][rg][cg * 4 + c4] = mx;
      redm[1][rg][cg * 4 + c4] = mn;
    }
  }
  __syncthreads();
  if (t < COUT) {
    float S = 0.f, Q = 0.f;
    #pragma unroll
    for (int g = 0; g < NG; g++) { S += red[0][g][t]; Q += red[1][g][t]; }
    psum[(size_t)t * NBLKS + blk] = S;
    psq [(size_t)t * NBLKS + blk] = Q;
    if constexpr (MM) {
      float mx = redm[0][0][t], mn = redm[1][0][t];
      #pragma unroll
      for (int g = 1; g < NG; g++) { mx = fmaxf(mx, redm[0][g][t]); mn = fminf(mn, redm[1][g][t]); }
      gmax[(size_t)blk * COUT + t] = mx;
      gmin[(size_t)blk * COUT + t] = mn;
    }
  }
}

// ---------------------------------------------------------------------------
// stats finalize (unchanged)
// ---------------------------------------------------------------------------
template <int NBLK>
__global__ __launch_bounds__(256)
void stats_final_kernel(const float* __restrict__ psum, const float* __restrict__ psq,
                        const float* __restrict__ g, const float* __restrict__ be,
                        float* __restrict__ ss_out) {
  const int c = blockIdx.x, t = threadIdx.x;
  float S = 0.f, Q = 0.f;
  for (int i = t; i < NBLK; i += 256) {
    S += psum[(size_t)c * NBLK + i];
    Q += psq [(size_t)c * NBLK + i];
  }
  __shared__ float sS[256], sQ[256];
  sS[t] = S; sQ[t] = Q;
  __syncthreads();
  #pragma unroll
  for (int off = 128; off; off >>= 1) {
    if (t < off) { sS[t] += sS[t + off]; sQ[t] += sQ[t + off]; }
    __syncthreads();
  }
  if (t == 0) {
    const float inv = 1.0f / 262144.0f;
    float mean = sS[0] * inv;
    float var = sQ[0] * inv - mean * mean;
    float scale = g[c] / sqrtf(var + 1e-3f);
    ss_out[c] = scale;
    ss_out[128 + c] = be[c] - mean * scale;
  }
}

// pool finalize (unchanged)
__global__ __launch_bounds__(128)
void pool_final_kernel(const float* __restrict__ gmax, const float* __restrict__ gmin,
                       const float* __restrict__ ss2, float* __restrict__ out1) {
  const int blk = blockIdx.x, c = threadIdx.x;
  const float sc = ss2[c], sh = ss2[128 + c];
  float v = (sc >= 0.f) ? gmax[(size_t)blk * C3 + c] : gmin[(size_t)blk * C3 + c];
  out1[(size_t)blk * C3 + c] = fmaxf(fmaf(v, sc, sh), 0.f);
}

extern "C" void kernel_launch(void* const* d_in, const int* in_sizes, int n_in,
                              void* d_out, int out_size, void* d_ws, size_t ws_size,
                              hipStream_t stream) {
  const float* xyz = (const float*)d_in[0];
  const float* pts = (const float*)d_in[1];
  const float* w0 = (const float*)d_in[2];
  const float* b0 = (const float*)d_in[3];
  const float* g0 = (const float*)d_in[4];
  const float* be0 = (const float*)d_in[5];
  const float* w1 = (const float*)d_in[6];
  const float* b1 = (const float*)d_in[7];
  const float* g1 = (const float*)d_in[8];
  const float* be1 = (const float*)d_in[9];
  const float* w2 = (const float*)d_in[10];
  const float* b2 = (const float*)d_in[11];
  const float* g2 = (const float*)d_in[12];
  const float* be2 = (const float*)d_in[13];

  float* out = (float*)d_out;
  float* cent = out;                       // [8,1024,3]
  float* out1 = out + (size_t)NB * NC * 3; // [8,1024,128]

  char* ws = (char*)d_ws;
  float* ssA  = (float*)(ws + OFF_SS);
  float* y0   = (float*)(ws + OFF_Y0);
  float* y1   = (float*)(ws + OFF_Y1);
  float* psum = (float*)(ws + OFF_PSUM);
  float* psq  = (float*)(ws + OFF_PSQ);
  float* gmx  = (float*)(ws + OFF_GMX);
  float* gmn  = (float*)(ws + OFF_GMN);

  fps_kernel<<<dim3(NB), dim3(256), 0, stream>>>(xyz, cent);

  ball_dense0_kernel<<<dim3(NB * NC), dim3(256), 0, stream>>>(
      xyz, pts, cent, w0, b0, y0, psum, psq);
  stats_final_kernel<8192><<<dim3(64), dim3(256), 0, stream>>>(psum, psq, g0, be0, ssA + 0 * 256);

  dense_mid_kernel<64, 64, 16, 4096, false><<<dim3(ROWS_TOT / 64), dim3(256), 0, stream>>>(
      y0, ssA + 0 * 256, w1, b1, y1, psum, psq, nullptr, nullptr);
  stats_final_kernel<4096><<<dim3(64), dim3(256), 0, stream>>>(psum, psq, g1, be1, ssA + 1 * 256);

  dense_mid_kernel<32, 128, 32, 8192, true><<<dim3(ROWS_TOT / 32), dim3(256), 0, stream>>>(
      y1, ssA + 1 * 256, w2, b2, nullptr, psum, psq, gmx, gmn);
  stats_final_kernel<8192><<<dim3(128), dim3(256), 0, stream>>>(psum, psq, g2, be2, ssA + 2 * 256);

  pool_final_kernel<<<dim3(NB * NC), dim3(128), 0, stream>>>(gmx, gmn, ssA + 2 * 256, out1);

  (void)in_sizes; (void)n_in; (void)out_size; (void)ws_size;
}